// Round 1
// 517.444 us; speedup vs baseline: 1.0876x; 1.0876x over previous
//
#include <hip/hip_runtime.h>
#include <cstdint>
#include <cstddef>

typedef unsigned short u16;
typedef unsigned int u32;

typedef unsigned short u16x8 __attribute__((ext_vector_type(8)));
typedef __bf16 bf16x8 __attribute__((ext_vector_type(8)));
typedef float f32x4 __attribute__((ext_vector_type(4)));
typedef float f32x8 __attribute__((ext_vector_type(8)));

#define NB   128
#define NL   192
#define NTOK (NB * NL)   // 24576
#define DIM  512
#define HID  2048

static __device__ __forceinline__ float bf2f(u16 h) {
    union { u32 u; float f; } v; v.u = ((u32)h) << 16; return v.f;
}
static __device__ __forceinline__ u16 f2bf(float f) {
    union { float f; u32 u; } v; v.f = f;
    u32 u = v.u + 0x7FFF + ((v.u >> 16) & 1);  // RNE
    return (u16)(u >> 16);
}

// -------- weight transpose + cast: in f32 (K,N) -> out bf16 (N,K) --------
__global__ void transpose_f2b(const float* __restrict__ in, u16* __restrict__ out,
                              int K, int N) {
    __shared__ float tile[32][33];
    int tx = threadIdx.x & 31, ty = threadIdx.x >> 5;  // 32 x 8
    int n0 = blockIdx.x * 32, k0 = blockIdx.y * 32;
#pragma unroll
    for (int i = 0; i < 4; i++)
        tile[ty + i * 8][tx] = in[(size_t)(k0 + ty + i * 8) * N + n0 + tx];
    __syncthreads();
#pragma unroll
    for (int i = 0; i < 4; i++)
        out[(size_t)(n0 + ty + i * 8) * K + k0 + tx] = f2bf(tile[tx][ty + i * 8]);
}

// -------- embedding: emb[t=l*B+b][d] = sum of 5 f32 tables; f32 + bf16 out ----
static __device__ __forceinline__ void add8f(float* acc, const float* p) {
    f32x8 v = *(const f32x8*)p;
#pragma unroll
    for (int i = 0; i < 8; i++) acc[i] += v[i];
}

__global__ void embed_kernel(const int* __restrict__ element, const int* __restrict__ aroma,
                             const int* __restrict__ charge, const int* __restrict__ segment,
                             const float* __restrict__ pe, const float* __restrict__ E_elem,
                             const float* __restrict__ E_charge, const float* __restrict__ E_aroma,
                             const float* __restrict__ E_seg,
                             float* __restrict__ emb32, u16* __restrict__ emb16) {
    int t = blockIdx.x * 4 + (threadIdx.x >> 6);  // one wave per token
    int lane = threadIdx.x & 63;
    int l = t >> 7, b = t & 127;                  // t = l*128 + b
    int d = lane * 8;
    int idx = b * NL + l;
    int e = element[idx];
    int a = aroma[idx];
    int c = charge[idx] + 6;
    int s = segment[idx];
    float acc[8] = {0, 0, 0, 0, 0, 0, 0, 0};
    add8f(acc, E_elem  + (size_t)e * DIM + d);
    add8f(acc, pe      + (size_t)l * DIM + d);
    add8f(acc, E_aroma + (size_t)a * DIM + d);
    add8f(acc, E_charge+ (size_t)c * DIM + d);
    add8f(acc, E_seg   + (size_t)s * DIM + d);
    f32x8 o32; u16x8 o16;
#pragma unroll
    for (int i = 0; i < 8; i++) { o32[i] = acc[i]; o16[i] = f2bf(acc[i]); }
    *(f32x8*)(emb32 + (size_t)t * DIM + d) = o32;
    *(u16x8*)(emb16 + (size_t)t * DIM + d) = o16;
}

// -------- GEMM: C[M,N] = A[M,K] @ BT[N,K]^T (+f32 bias, relu, bf16/f32 resid) --
// 128x256 block tile, 4 waves each 64x128 (4x8 frags of 16x16x32 MFMA).
// Triple-buffered LDS, global_load_lds width=16, prefetch distance 2 tiles,
// counted waits (steady state vmcnt(12) = wait own 6 oldest only).
// This round's changes vs previous best:
//  * T2: LDS chunk-XOR swizzle (chunk ^= (row>>1)&3), applied via pre-swizzled
//    GLOBAL source address (gll dest must stay linear, m104) + swizzled ds_read.
//    Kills the 8-way bank conflict of 64B-stride fr-lanes (4.7M cyc measured).
//  * tail fix: no dummy reloads (was +19% staging traffic at K=512); tail waits
//    step down vmcnt(12)->(6)->(0).
//  * T5: s_setprio(1) around the MFMA cluster.
//  * T1: XCD-bijective, N-fastest block swizzle -> the 8 N-tiles sharing an
//    A-panel are consecutive on one XCD (A chunk ~3MB + B 2MB ~ L2-resident).
//  * coalesced epilogue: bias/relu/resid applied in-register (single f2bf
//    rounding), bf16 tile staged to LDS (stride 264 u16), then dwordx4 stores.
__global__ __launch_bounds__(256, 2) void gemm_bt(
    const u16* __restrict__ A, const u16* __restrict__ BT,
    const float* __restrict__ bias, const u16* __restrict__ resid16,
    const float* __restrict__ resid32,
    u16* __restrict__ C, int M, int N, int K, int do_relu) {
    __shared__ __align__(16) u16 smem[3 * 128 * 32 + 3 * 256 * 32];  // 72 KB
    u16* As = smem;                   // [3][128*32]
    u16* Bs = smem + 3 * 128 * 32;    // [3][256*32]

    const int tid  = threadIdx.x;
    const int wave = tid >> 6;
    const int lane = tid & 63;

    // XCD-aware swizzle (bijective when nwg%8==0 -- all our grids), N-fastest.
    const int nwg = gridDim.x;
    const int bid = blockIdx.x;
    const int wg  = ((nwg & 7) == 0) ? ((bid & 7) * (nwg >> 3) + (bid >> 3)) : bid;
    const int nt  = N >> 8;                 // N-tiles of 256
    const int m0  = (wg / nt) * 128;
    const int n0  = (wg % nt) * 256;

    const int wm = (wave >> 1) * 64;    // wave's 64-row half
    const int wn = (wave & 1) * 128;    // wave's 128-col half
    const int lr = lane >> 2;           // staging: row within 16-row group
    // staging k-chunk, XOR-swizzled by (row>>1)&3 so the LDS tile is swizzled
    // while the gll destination stays linear (pre-swizzled-source pattern).
    const int lc = (((lane & 3) ^ ((lr >> 1) & 3)) * 8);
    const int fr = lane & 15;           // fragment row/col
    const int fq = lane >> 4;           // fragment k-quad
    const int fc = ((fq ^ ((fr >> 1) & 3)) * 8);   // swizzled read chunk (u16)

    f32x4 acc[4][8] = {};

    // wave w stages A rows {w*16+lr, 64+w*16+lr}, B rows {w*16+lr + 0,64,128,192}
    const u16* Ag0 = A  + (size_t)(m0 + wave * 16 + lr) * K + lc;
    const u16* Ag1 = Ag0 + (size_t)64 * K;
    const u16* Bg0 = BT + (size_t)(n0 + wave * 16 + lr) * K + lc;
    const u16* Bg1 = Bg0 + (size_t)64 * K;
    const u16* Bg2 = Bg0 + (size_t)128 * K;
    const u16* Bg3 = Bg0 + (size_t)192 * K;
    const int sA0 = (wave * 16) * 32;          // wave-uniform LDS offsets (u16)
    const int sA1 = (64 + wave * 16) * 32;
    const int sB0 = (wave * 16) * 32;
    const int sB1 = (64 + wave * 16) * 32;
    const int sB2 = (128 + wave * 16) * 32;
    const int sB3 = (192 + wave * 16) * 32;

#define GLL(gp, lp) __builtin_amdgcn_global_load_lds(                            \
        (const __attribute__((address_space(1))) void*)(gp),                     \
        (__attribute__((address_space(3))) void*)(lp), 16, 0, 0)
#define STAGE(buf, k0) do {                                                      \
    GLL(Ag0 + (k0), &As[(buf) * 4096 + sA0]);                                    \
    GLL(Ag1 + (k0), &As[(buf) * 4096 + sA1]);                                    \
    GLL(Bg0 + (k0), &Bs[(buf) * 8192 + sB0]);                                    \
    GLL(Bg1 + (k0), &Bs[(buf) * 8192 + sB1]);                                    \
    GLL(Bg2 + (k0), &Bs[(buf) * 8192 + sB2]);                                    \
    GLL(Bg3 + (k0), &Bs[(buf) * 8192 + sB3]);                                    \
} while (0)

    const int kIters = K >> 5;   // K is 512 or 2048 here
    STAGE(0, 0);          // 6 loads in flight
    STAGE(1, 32);         // 12
    STAGE(2, 64);         // 18

    int cur = 0;
    for (int k = 0; k < kIters; ++k) {
        // drain own 6 oldest loads (tile k); later tiles stay in flight.
        if (k + 2 < kIters)
            asm volatile("s_waitcnt vmcnt(12)\n\ts_barrier" ::: "memory");
        else if (k + 2 == kIters)
            asm volatile("s_waitcnt vmcnt(6)\n\ts_barrier" ::: "memory");
        else
            asm volatile("s_waitcnt vmcnt(0)\n\ts_barrier" ::: "memory");

        const u16* Ab = &As[cur * 4096];
        const u16* Bb = &Bs[cur * 8192];
        bf16x8 af[4], bg[8];
#pragma unroll
        for (int i = 0; i < 4; i++)
            af[i] = *(const bf16x8*)(&Ab[(wm + i * 16 + fr) * 32 + fc]);
#pragma unroll
        for (int j = 0; j < 8; j++)
            bg[j] = *(const bf16x8*)(&Bb[(wn + j * 16 + fr) * 32 + fc]);

        __builtin_amdgcn_s_setprio(1);
#pragma unroll
        for (int i = 0; i < 4; i++)
#pragma unroll
            for (int j = 0; j < 8; j++)
                acc[i][j] = __builtin_amdgcn_mfma_f32_16x16x32_bf16(
                    af[i], bg[j], acc[i][j], 0, 0, 0);
        __builtin_amdgcn_s_setprio(0);

        if (k + 3 < kIters) {
            // all waves done reading buf cur -> safe to overwrite with tile k+3.
            asm volatile("s_barrier" ::: "memory");
            STAGE(cur, (k + 3) << 5);
        }
        cur = (cur == 2) ? 0 : cur + 1;
    }
#undef STAGE
#undef GLL

    // ---- epilogue: bias/relu/resid in-register, stage bf16 tile to LDS, ----
    // ---- then fully-coalesced dwordx4 stores (was 128 scalar 2B stores). ----
    // C/D layout: col = lane&15 (n), row = (lane>>4)*4 + reg (m)
    __syncthreads();   // full drain (vmcnt/lgkm) + all waves past final reads
#define CSTR 264       // 256 + 8 u16 pad: fq-row groups land 2-way max
#pragma unroll
    for (int j = 0; j < 8; j++) {
        int n = n0 + wn + j * 16 + fr;
        float bv = bias[n];
#pragma unroll
        for (int i = 0; i < 4; i++) {
#pragma unroll
            for (int r = 0; r < 4; r++) {
                int m = m0 + wm + i * 16 + fq * 4 + r;
                float v = acc[i][j][r] + bv;
                if (do_relu) v = fmaxf(v, 0.0f);
                if (resid16) v += bf2f(resid16[(size_t)m * N + n]);
                if (resid32) v += resid32[(size_t)m * N + n];
                smem[(wm + i * 16 + fq * 4 + r) * CSTR + wn + j * 16 + fr] = f2bf(v);
            }
        }
    }
    __syncthreads();
    {
        const int erow = tid >> 5;         // 0..7
        const int ecol = (tid & 31) * 8;   // 32 lanes x 8 u16 = 256 cols
#pragma unroll
        for (int rr = 0; rr < 16; ++rr) {
            int row = rr * 8 + erow;
            *(u16x8*)(C + (size_t)(m0 + row) * N + n0 + ecol) =
                *(const u16x8*)(&smem[row * CSTR + ecol]);
        }
    }
#undef CSTR
}

// -------- aggregation + final residual (in-place on d_out, f32) --------
// out[t=l*B+b][d] = emb32[t][d] + sum_m (bond[b,l,m]!=l) * msg[bond*B+b][d]
__global__ void agg_kernel(const float* __restrict__ emb32, const u16* __restrict__ msg,
                           const int* __restrict__ bond, float* __restrict__ out) {
    int t = blockIdx.x * 4 + (threadIdx.x >> 6);  // one wave per token
    int lane = threadIdx.x & 63;
    int l = t >> 7, b = t & 127;
    int d = lane * 8;
    float acc[8];
    {
        f32x8 v = *(const f32x8*)(emb32 + (size_t)t * DIM + d);
#pragma unroll
        for (int i = 0; i < 8; i++) acc[i] = v[i];
    }
    const int* bp = bond + ((size_t)b * NL + l) * 6;
#pragma unroll
    for (int m = 0; m < 6; m++) {
        int j = bp[m];
        if (j != l) {  // wave-uniform branch
            u16x8 g = *(const u16x8*)(msg + ((size_t)j * NB + b) * DIM + d);
#pragma unroll
            for (int i = 0; i < 8; i++) acc[i] += bf2f(g[i]);
        }
    }
    f32x8 o;
#pragma unroll
    for (int i = 0; i < 8; i++) o[i] = acc[i];
    *(f32x8*)(out + (size_t)t * DIM + d) = o;
}

extern "C" void kernel_launch(void* const* d_in, const int* in_sizes, int n_in,
                              void* d_out, int out_size, void* d_ws, size_t ws_size,
                              hipStream_t stream) {
    const int* element = (const int*)d_in[0];
    const int* bond    = (const int*)d_in[1];
    const int* aroma   = (const int*)d_in[2];
    const int* charge  = (const int*)d_in[3];
    const int* segment = (const int*)d_in[4];
    const float* pe      = (const float*)d_in[5];
    const float* E_elem  = (const float*)d_in[6];
    const float* E_charge= (const float*)d_in[7];
    const float* E_aroma = (const float*)d_in[8];
    const float* E_seg   = (const float*)d_in[9];
    const float* W1 = (const float*)d_in[10];
    const float* b1 = (const float*)d_in[11];
    const float* W2 = (const float*)d_in[12];
    const float* b2 = (const float*)d_in[13];
    const float* W3 = (const float*)d_in[14];
    const float* b3 = (const float*)d_in[15];
    const float* W4 = (const float*)d_in[16];
    const float* b4 = (const float*)d_in[17];
    const float* W5 = (const float*)d_in[18];
    const float* b5 = (const float*)d_in[19];

    // f32 emb lives in d_out (50 MiB); agg rewrites d_out in place at the end.
    float* emb32 = (float*)d_out;

    // dynamic ws layout — never exceed ws_size
    char* ws = (char*)d_ws;
    size_t woff = 0;
    auto take = [&](size_t bytes) -> u16* {
        u16* p = (u16*)(ws + woff);
        woff += (bytes + 255) & ~(size_t)255;
        return p;
    };
    u16* W1T = take((size_t)HID * DIM * 2);   // 2048x512 bf16
    u16* W2T = take((size_t)DIM * HID * 2);   // 512x2048
    u16* W3T = take((size_t)HID * DIM * 2);
    u16* W4T = take((size_t)DIM * HID * 2);
    u16* W5T = take((size_t)DIM * DIM * 2);
    u16* emb16 = take((size_t)NTOK * DIM * 2);  // 24 MiB
    u16* msg   = take((size_t)NTOK * DIM * 2);  // 24 MiB

    // pick largest M-chunk that fits: h(CM x HID) + xa,xb(CM x DIM), bf16
    static const int ncs[] = {1, 2, 3, 4, 6, 8, 12, 16, 24, 32, 48, 64, 96, 192};
    int CM = 128;
    for (int nc : ncs) {
        int cm = NTOK / nc;
        size_t need = woff + ((size_t)cm * HID * 2 + 256)
                           + ((size_t)cm * DIM * 2 + 256) * 2;
        if (need <= ws_size) { CM = cm; break; }
    }
    u16* hC  = take((size_t)CM * HID * 2);
    u16* xaC = take((size_t)CM * DIM * 2);
    u16* xbC = take((size_t)CM * DIM * 2);

    // weight transposes + cast: f32 (K,N) -> bf16 (N,K)
    transpose_f2b<<<dim3(HID / 32, DIM / 32), 256, 0, stream>>>(W1, W1T, DIM, HID);
    transpose_f2b<<<dim3(DIM / 32, HID / 32), 256, 0, stream>>>(W2, W2T, HID, DIM);
    transpose_f2b<<<dim3(HID / 32, DIM / 32), 256, 0, stream>>>(W3, W3T, DIM, HID);
    transpose_f2b<<<dim3(DIM / 32, HID / 32), 256, 0, stream>>>(W4, W4T, HID, DIM);
    transpose_f2b<<<dim3(DIM / 32, DIM / 32), 256, 0, stream>>>(W5, W5T, DIM, DIM);

    embed_kernel<<<NTOK / 4, 256, 0, stream>>>(element, aroma, charge, segment, pe,
                                               E_elem, E_charge, E_aroma, E_seg,
                                               emb32, emb16);

    // MLP per M-chunk: x += relu(x@W1+b1)@W2+b2 ; x += relu(x@W3+b3)@W4+b4 ; msg = x@W5+b5
    for (int c0 = 0; c0 < NTOK; c0 += CM) {
        const u16* x16 = emb16 + (size_t)c0 * DIM;
        const float* x32 = emb32 + (size_t)c0 * DIM;
        u16* msgC = msg + (size_t)c0 * DIM;
        int mt = CM / 128;
        gemm_bt<<<dim3(mt * (HID / 256)), 256, 0, stream>>>(x16, W1T, b1, nullptr, nullptr, hC,  CM, HID, DIM, 1);
        gemm_bt<<<dim3(mt * (DIM / 256)), 256, 0, stream>>>(hC,  W2T, b2, nullptr, x32,     xaC, CM, DIM, HID, 0);
        gemm_bt<<<dim3(mt * (HID / 256)), 256, 0, stream>>>(xaC, W3T, b3, nullptr, nullptr, hC,  CM, HID, DIM, 1);
        gemm_bt<<<dim3(mt * (DIM / 256)), 256, 0, stream>>>(hC,  W4T, b4, xaC,    nullptr,  xbC, CM, DIM, HID, 0);
        gemm_bt<<<dim3(mt * (DIM / 256)), 256, 0, stream>>>(xbC, W5T, b5, nullptr, nullptr, msgC, CM, DIM, DIM, 0);
    }

    agg_kernel<<<NTOK / 4, 256, 0, stream>>>(emb32, msg, bond, (float*)d_out);
}

// Round 2
// 505.696 us; speedup vs baseline: 1.1128x; 1.0232x over previous
//
#include <hip/hip_runtime.h>
#include <cstdint>
#include <cstddef>

typedef unsigned short u16;
typedef unsigned int u32;

typedef unsigned short u16x8 __attribute__((ext_vector_type(8)));
typedef __bf16 bf16x8 __attribute__((ext_vector_type(8)));
typedef float f32x4 __attribute__((ext_vector_type(4)));
typedef float f32x8 __attribute__((ext_vector_type(8)));

#define NB   128
#define NL   192
#define NTOK (NB * NL)   // 24576
#define DIM  512
#define HID  2048

static __device__ __forceinline__ float bf2f(u16 h) {
    union { u32 u; float f; } v; v.u = ((u32)h) << 16; return v.f;
}
static __device__ __forceinline__ u16 f2bf(float f) {
    union { float f; u32 u; } v; v.f = f;
    u32 u = v.u + 0x7FFF + ((v.u >> 16) & 1);  // RNE
    return (u16)(u >> 16);
}

// -------- weight transpose + cast: in f32 (K,N) -> out bf16 (N,K) --------
__global__ void transpose_f2b(const float* __restrict__ in, u16* __restrict__ out,
                              int K, int N) {
    __shared__ float tile[32][33];
    int tx = threadIdx.x & 31, ty = threadIdx.x >> 5;  // 32 x 8
    int n0 = blockIdx.x * 32, k0 = blockIdx.y * 32;
#pragma unroll
    for (int i = 0; i < 4; i++)
        tile[ty + i * 8][tx] = in[(size_t)(k0 + ty + i * 8) * N + n0 + tx];
    __syncthreads();
#pragma unroll
    for (int i = 0; i < 4; i++)
        out[(size_t)(n0 + ty + i * 8) * K + k0 + tx] = f2bf(tile[tx][ty + i * 8]);
}

// -------- embedding: emb[t=l*B+b][d] = sum of 5 f32 tables; f32 + bf16 out ----
static __device__ __forceinline__ void add8f(float* acc, const float* p) {
    f32x8 v = *(const f32x8*)p;
#pragma unroll
    for (int i = 0; i < 8; i++) acc[i] += v[i];
}

__global__ void embed_kernel(const int* __restrict__ element, const int* __restrict__ aroma,
                             const int* __restrict__ charge, const int* __restrict__ segment,
                             const float* __restrict__ pe, const float* __restrict__ E_elem,
                             const float* __restrict__ E_charge, const float* __restrict__ E_aroma,
                             const float* __restrict__ E_seg,
                             float* __restrict__ emb32, u16* __restrict__ emb16) {
    int t = blockIdx.x * 4 + (threadIdx.x >> 6);  // one wave per token
    int lane = threadIdx.x & 63;
    int l = t >> 7, b = t & 127;                  // t = l*128 + b
    int d = lane * 8;
    int idx = b * NL + l;
    int e = element[idx];
    int a = aroma[idx];
    int c = charge[idx] + 6;
    int s = segment[idx];
    float acc[8] = {0, 0, 0, 0, 0, 0, 0, 0};
    add8f(acc, E_elem  + (size_t)e * DIM + d);
    add8f(acc, pe      + (size_t)l * DIM + d);
    add8f(acc, E_aroma + (size_t)a * DIM + d);
    add8f(acc, E_charge+ (size_t)c * DIM + d);
    add8f(acc, E_seg   + (size_t)s * DIM + d);
    f32x8 o32; u16x8 o16;
#pragma unroll
    for (int i = 0; i < 8; i++) { o32[i] = acc[i]; o16[i] = f2bf(acc[i]); }
    *(f32x8*)(emb32 + (size_t)t * DIM + d) = o32;
    *(u16x8*)(emb16 + (size_t)t * DIM + d) = o16;
}

// -------- GEMM: C[M,N] = A[M,K] @ BT[N,K]^T (+f32 bias, relu, bf16/f32 resid) --
// T3+T4 phase-split port of the 256^2 template:
//   256x256 block tile, BK=32, 512 threads = 8 waves (2M x 4N), per-wave 128x64
//   (acc[8][4] of 16x16x32 MFMA frags).
//   4 LDS staging buffers (A[256][32]+B[256][32] bf16 each = 128 KB), staging
//   lead = 3 K-tiles -> every boundary wait is a COUNTED vmcnt(8) (tiles t+1,
//   t+2 stay in flight; never drain to 0 in the loop; tail steps 8->4->0).
//   2 phases per K-tile, 16 MFMA each, mid-phase s_barrier, setprio(1) around
//   MFMA clusters (T5 -- pays only with phase-split per m218b).
// Race-freedom: stage of tile t+3 targets buf (t+3)&3, disjoint from bufs of
//   t,t+1,t+2; buf (t+3)&3 == (t-1)&3 whose last reads completed before the
//   boundary barrier ending tile t-1 (ds_read results are in regs before the
//   pre-MFMA lgkmcnt, which precedes that barrier). Boundary vmcnt(8)+barrier
//   guarantees ALL waves' tile-t stages landed before any wave reads tile t.
// Chunk-XOR swizzle (proven 0-conflict in round 1) via pre-swizzled global
//   source + swizzled ds_read; gll LDS dest stays linear (m104 rule).
// Requires M%256==0, N%256==0, K%32==0, K/32 >= 3 (all our shapes).
__global__ __launch_bounds__(512, 2) void gemm_bt(
    const u16* __restrict__ A, const u16* __restrict__ BT,
    const float* __restrict__ bias, const u16* __restrict__ resid16,
    const float* __restrict__ resid32,
    u16* __restrict__ C, int M, int N, int K, int do_relu) {
    // staging: As[4][256*32] @ 0, Bs[4][256*32] @ 32768 (u16) = 128 KB;
    // epilogue reuses smem as [256][264] u16 = 132 KB. Declared 135168 B.
    __shared__ __align__(16) u16 smem[256 * 264];

    const int tid  = threadIdx.x;
    const int wave = tid >> 6;
    const int lane = tid & 63;

    // XCD-aware swizzle (bijective when nwg%8==0 -- all our grids), N-fastest.
    const int nwg = gridDim.x;
    const int bid = blockIdx.x;
    const int wg  = ((nwg & 7) == 0) ? ((bid & 7) * (nwg >> 3) + (bid >> 3)) : bid;
    const int nt  = N >> 8;                 // N-tiles of 256
    const int m0  = (wg / nt) * 256;
    const int n0  = (wg % nt) * 256;

    const int wmh = wave >> 2;          // 0..1 : wave's A row-half (128 rows)
    const int wnq = wave & 3;           // 0..3 : wave's B row-quarter (64 rows)
    const int lr  = lane >> 2;          // staging: row within 16-row group
    const int lc  = (((lane & 3) ^ ((lr >> 1) & 3)) * 8);  // pre-swizzled src chunk
    const int fr  = lane & 15;          // fragment row/col
    const int fq  = lane >> 4;          // fragment k-quad
    const int fc  = ((fq ^ ((fr >> 1) & 3)) * 8);          // swizzled read chunk

    f32x4 acc[8][4] = {};

    // wave w stages operand rows {w*16+lr, 128+w*16+lr}
    const u16* Ag0 = A  + (size_t)(m0 + wave * 16 + lr) * K + lc;
    const u16* Ag1 = Ag0 + (size_t)128 * K;
    const u16* Bg0 = BT + (size_t)(n0 + wave * 16 + lr) * K + lc;
    const u16* Bg1 = Bg0 + (size_t)128 * K;
    const int sR0 = (wave * 16) * 32;        // wave-uniform LDS offsets (u16)
    const int sR1 = (128 + wave * 16) * 32;

#define GLL(gp, lp) __builtin_amdgcn_global_load_lds(                            \
        (const __attribute__((address_space(1))) void*)(gp),                     \
        (__attribute__((address_space(3))) void*)(lp), 16, 0, 0)
#define STAGE_A(buf, kt) do {                                                    \
    GLL(Ag0 + (size_t)(kt) * 32, &smem[(buf) * 8192 + sR0]);                     \
    GLL(Ag1 + (size_t)(kt) * 32, &smem[(buf) * 8192 + sR1]);                     \
} while (0)
#define STAGE_B(buf, kt) do {                                                    \
    GLL(Bg0 + (size_t)(kt) * 32, &smem[32768 + (buf) * 8192 + sR0]);             \
    GLL(Bg1 + (size_t)(kt) * 32, &smem[32768 + (buf) * 8192 + sR1]);             \
} while (0)

    const int nk = K >> 5;   // 16 or 64 here; >= 3 required
    STAGE_A(0, 0); STAGE_B(0, 0);   // oldest-first issue order: per-tile A,B
    STAGE_A(1, 1); STAGE_B(1, 1);
    STAGE_A(2, 2); STAGE_B(2, 2);   // 12 loads in flight

    for (int t = 0; t < nk; ++t) {
        // ---- boundary: tile t landed (own 4 oldest); t+1,t+2 stay in flight.
        if (t + 2 < nk)
            asm volatile("s_waitcnt vmcnt(8)\n\ts_barrier" ::: "memory");
        else if (t + 1 < nk)
            asm volatile("s_waitcnt vmcnt(4)\n\ts_barrier" ::: "memory");
        else
            asm volatile("s_waitcnt vmcnt(0)\n\ts_barrier" ::: "memory");

        const u16* Ab = &smem[(t & 3) * 8192];
        const u16* Bb = &smem[32768 + (t & 3) * 8192];

        // ---- phase 1: read A i0-3 + B j0-3, stage A(t+3), 16 MFMA ----------
        bf16x8 af[4], bg[4];
#pragma unroll
        for (int i = 0; i < 4; i++)
            af[i] = *(const bf16x8*)(&Ab[(wmh * 128 + i * 16 + fr) * 32 + fc]);
#pragma unroll
        for (int j = 0; j < 4; j++)
            bg[j] = *(const bf16x8*)(&Bb[(wnq * 64 + j * 16 + fr) * 32 + fc]);
        if (t + 3 < nk) STAGE_A((t + 3) & 3, t + 3);

        __builtin_amdgcn_s_setprio(1);
#pragma unroll
        for (int i = 0; i < 4; i++)
#pragma unroll
            for (int j = 0; j < 4; j++)
                acc[i][j] = __builtin_amdgcn_mfma_f32_16x16x32_bf16(
                    af[i], bg[j], acc[i][j], 0, 0, 0);
        __builtin_amdgcn_s_setprio(0);

        asm volatile("s_barrier" ::: "memory");   // phase-lock (template)

        // ---- phase 2: read A i4-7, stage B(t+3), 16 MFMA -------------------
#pragma unroll
        for (int i = 0; i < 4; i++)
            af[i] = *(const bf16x8*)(&Ab[(wmh * 128 + (i + 4) * 16 + fr) * 32 + fc]);
        if (t + 3 < nk) STAGE_B((t + 3) & 3, t + 3);

        __builtin_amdgcn_s_setprio(1);
#pragma unroll
        for (int i = 0; i < 4; i++)
#pragma unroll
            for (int j = 0; j < 4; j++)
                acc[i + 4][j] = __builtin_amdgcn_mfma_f32_16x16x32_bf16(
                    af[i], bg[j], acc[i + 4][j], 0, 0, 0);
        __builtin_amdgcn_s_setprio(0);
    }
#undef STAGE_A
#undef STAGE_B
#undef GLL

    // ---- epilogue: bias/relu/resid in-register, stage bf16 tile to LDS, ----
    // ---- then fully-coalesced dwordx4 stores. ------------------------------
    // C/D layout: col = lane&15 (n), row = (lane>>4)*4 + reg (m)
    __syncthreads();   // all waves past final LDS reads; all own vmem drained
#define CSTR 264       // 256 + 8 u16 pad
#pragma unroll
    for (int j = 0; j < 4; j++) {
        int n = n0 + wnq * 64 + j * 16 + fr;
        float bv = bias[n];
#pragma unroll
        for (int i = 0; i < 8; i++) {
#pragma unroll
            for (int r = 0; r < 4; r++) {
                int m = m0 + wmh * 128 + i * 16 + fq * 4 + r;
                float v = acc[i][j][r] + bv;
                if (do_relu) v = fmaxf(v, 0.0f);
                if (resid16) v += bf2f(resid16[(size_t)m * N + n]);
                if (resid32) v += resid32[(size_t)m * N + n];
                smem[(wmh * 128 + i * 16 + fq * 4 + r) * CSTR + wnq * 64 + j * 16 + fr] = f2bf(v);
            }
        }
    }
    __syncthreads();
    {
        const int erow = tid >> 5;         // 0..15
        const int ecol = (tid & 31) * 8;   // 32 lanes x 8 u16 = 256 cols
#pragma unroll
        for (int rr = 0; rr < 16; ++rr) {
            int row = rr * 16 + erow;
            *(u16x8*)(C + (size_t)(m0 + row) * N + n0 + ecol) =
                *(const u16x8*)(&smem[row * CSTR + ecol]);
        }
    }
#undef CSTR
}

// -------- aggregation + final residual (in-place on d_out, f32) --------
// out[t=l*B+b][d] = emb32[t][d] + sum_m (bond[b,l,m]!=l) * msg[bond*B+b][d]
__global__ void agg_kernel(const float* __restrict__ emb32, const u16* __restrict__ msg,
                           const int* __restrict__ bond, float* __restrict__ out) {
    int t = blockIdx.x * 4 + (threadIdx.x >> 6);  // one wave per token
    int lane = threadIdx.x & 63;
    int l = t >> 7, b = t & 127;
    int d = lane * 8;
    float acc[8];
    {
        f32x8 v = *(const f32x8*)(emb32 + (size_t)t * DIM + d);
#pragma unroll
        for (int i = 0; i < 8; i++) acc[i] = v[i];
    }
    const int* bp = bond + ((size_t)b * NL + l) * 6;
#pragma unroll
    for (int m = 0; m < 6; m++) {
        int j = bp[m];
        if (j != l) {  // wave-uniform branch
            u16x8 g = *(const u16x8*)(msg + ((size_t)j * NB + b) * DIM + d);
#pragma unroll
            for (int i = 0; i < 8; i++) acc[i] += bf2f(g[i]);
        }
    }
    f32x8 o;
#pragma unroll
    for (int i = 0; i < 8; i++) o[i] = acc[i];
    *(f32x8*)(out + (size_t)t * DIM + d) = o;
}

extern "C" void kernel_launch(void* const* d_in, const int* in_sizes, int n_in,
                              void* d_out, int out_size, void* d_ws, size_t ws_size,
                              hipStream_t stream) {
    const int* element = (const int*)d_in[0];
    const int* bond    = (const int*)d_in[1];
    const int* aroma   = (const int*)d_in[2];
    const int* charge  = (const int*)d_in[3];
    const int* segment = (const int*)d_in[4];
    const float* pe      = (const float*)d_in[5];
    const float* E_elem  = (const float*)d_in[6];
    const float* E_charge= (const float*)d_in[7];
    const float* E_aroma = (const float*)d_in[8];
    const float* E_seg   = (const float*)d_in[9];
    const float* W1 = (const float*)d_in[10];
    const float* b1 = (const float*)d_in[11];
    const float* W2 = (const float*)d_in[12];
    const float* b2 = (const float*)d_in[13];
    const float* W3 = (const float*)d_in[14];
    const float* b3 = (const float*)d_in[15];
    const float* W4 = (const float*)d_in[16];
    const float* b4 = (const float*)d_in[17];
    const float* W5 = (const float*)d_in[18];
    const float* b5 = (const float*)d_in[19];

    // f32 emb lives in d_out (50 MiB); agg rewrites d_out in place at the end.
    float* emb32 = (float*)d_out;

    // dynamic ws layout — never exceed ws_size
    char* ws = (char*)d_ws;
    size_t woff = 0;
    auto take = [&](size_t bytes) -> u16* {
        u16* p = (u16*)(ws + woff);
        woff += (bytes + 255) & ~(size_t)255;
        return p;
    };
    u16* W1T = take((size_t)HID * DIM * 2);   // 2048x512 bf16
    u16* W2T = take((size_t)DIM * HID * 2);   // 512x2048
    u16* W3T = take((size_t)HID * DIM * 2);
    u16* W4T = take((size_t)DIM * HID * 2);
    u16* W5T = take((size_t)DIM * DIM * 2);
    u16* emb16 = take((size_t)NTOK * DIM * 2);  // 24 MiB
    u16* msg   = take((size_t)NTOK * DIM * 2);  // 24 MiB

    // pick largest M-chunk that fits: h(CM x HID) + xa,xb(CM x DIM), bf16.
    // CM must be a multiple of 256 (gemm tile height).
    static const int ncs[] = {1, 2, 3, 4, 6, 8, 12, 16, 24, 32, 48, 96};
    int CM = 256;
    for (int nc : ncs) {
        int cm = NTOK / nc;
        if (cm % 256 != 0) continue;
        size_t need = woff + ((size_t)cm * HID * 2 + 256)
                           + ((size_t)cm * DIM * 2 + 256) * 2;
        if (need <= ws_size) { CM = cm; break; }
    }
    u16* hC  = take((size_t)CM * HID * 2);
    u16* xaC = take((size_t)CM * DIM * 2);
    u16* xbC = take((size_t)CM * DIM * 2);

    // weight transposes + cast: f32 (K,N) -> bf16 (N,K)
    transpose_f2b<<<dim3(HID / 32, DIM / 32), 256, 0, stream>>>(W1, W1T, DIM, HID);
    transpose_f2b<<<dim3(DIM / 32, HID / 32), 256, 0, stream>>>(W2, W2T, HID, DIM);
    transpose_f2b<<<dim3(HID / 32, DIM / 32), 256, 0, stream>>>(W3, W3T, DIM, HID);
    transpose_f2b<<<dim3(DIM / 32, HID / 32), 256, 0, stream>>>(W4, W4T, HID, DIM);
    transpose_f2b<<<dim3(DIM / 32, DIM / 32), 256, 0, stream>>>(W5, W5T, DIM, DIM);

    embed_kernel<<<NTOK / 4, 256, 0, stream>>>(element, aroma, charge, segment, pe,
                                               E_elem, E_charge, E_aroma, E_seg,
                                               emb32, emb16);

    // MLP per M-chunk: x += relu(x@W1+b1)@W2+b2 ; x += relu(x@W3+b3)@W4+b4 ; msg = x@W5+b5
    for (int c0 = 0; c0 < NTOK; c0 += CM) {
        const u16* x16 = emb16 + (size_t)c0 * DIM;
        const float* x32 = emb32 + (size_t)c0 * DIM;
        u16* msgC = msg + (size_t)c0 * DIM;
        int mt = CM / 256;
        gemm_bt<<<dim3(mt * (HID / 256)), 512, 0, stream>>>(x16, W1T, b1, nullptr, nullptr, hC,  CM, HID, DIM, 1);
        gemm_bt<<<dim3(mt * (DIM / 256)), 512, 0, stream>>>(hC,  W2T, b2, nullptr, x32,     xaC, CM, DIM, HID, 0);
        gemm_bt<<<dim3(mt * (HID / 256)), 512, 0, stream>>>(xaC, W3T, b3, nullptr, nullptr, hC,  CM, HID, DIM, 1);
        gemm_bt<<<dim3(mt * (DIM / 256)), 512, 0, stream>>>(hC,  W4T, b4, xaC,    nullptr,  xbC, CM, DIM, HID, 0);
        gemm_bt<<<dim3(mt * (DIM / 256)), 512, 0, stream>>>(xbC, W5T, b5, nullptr, nullptr, msgC, CM, DIM, DIM, 0);
    }

    agg_kernel<<<NTOK / 4, 256, 0, stream>>>(emb32, msg, bond, (float*)d_out);
}

// Round 3
// 487.674 us; speedup vs baseline: 1.1539x; 1.0370x over previous
//
#include <hip/hip_runtime.h>
#include <cstdint>
#include <cstddef>

typedef unsigned short u16;
typedef unsigned int u32;

typedef unsigned short u16x8 __attribute__((ext_vector_type(8)));
typedef __bf16 bf16x8 __attribute__((ext_vector_type(8)));
typedef float f32x4 __attribute__((ext_vector_type(4)));
typedef float f32x8 __attribute__((ext_vector_type(8)));

#define NB   128
#define NL   192
#define NTOK (NB * NL)   // 24576
#define DIM  512
#define HID  2048

static __device__ __forceinline__ float bf2f(u16 h) {
    union { u32 u; float f; } v; v.u = ((u32)h) << 16; return v.f;
}
static __device__ __forceinline__ u16 f2bf(float f) {
    union { float f; u32 u; } v; v.f = f;
    u32 u = v.u + 0x7FFF + ((v.u >> 16) & 1);  // RNE
    return (u16)(u >> 16);
}

// -------- weight transpose + cast: in f32 (K,N) -> out bf16 (N,K) --------
__global__ void transpose_f2b(const float* __restrict__ in, u16* __restrict__ out,
                              int K, int N) {
    __shared__ float tile[32][33];
    int tx = threadIdx.x & 31, ty = threadIdx.x >> 5;  // 32 x 8
    int n0 = blockIdx.x * 32, k0 = blockIdx.y * 32;
#pragma unroll
    for (int i = 0; i < 4; i++)
        tile[ty + i * 8][tx] = in[(size_t)(k0 + ty + i * 8) * N + n0 + tx];
    __syncthreads();
#pragma unroll
    for (int i = 0; i < 4; i++)
        out[(size_t)(n0 + ty + i * 8) * K + k0 + tx] = f2bf(tile[tx][ty + i * 8]);
}

// -------- embedding: emb[t=l*B+b][d] = sum of 5 f32 tables; f32 + bf16 out ----
static __device__ __forceinline__ void add8f(float* acc, const float* p) {
    f32x8 v = *(const f32x8*)p;
#pragma unroll
    for (int i = 0; i < 8; i++) acc[i] += v[i];
}

__global__ void embed_kernel(const int* __restrict__ element, const int* __restrict__ aroma,
                             const int* __restrict__ charge, const int* __restrict__ segment,
                             const float* __restrict__ pe, const float* __restrict__ E_elem,
                             const float* __restrict__ E_charge, const float* __restrict__ E_aroma,
                             const float* __restrict__ E_seg,
                             float* __restrict__ emb32, u16* __restrict__ emb16) {
    int t = blockIdx.x * 4 + (threadIdx.x >> 6);  // one wave per token
    int lane = threadIdx.x & 63;
    int l = t >> 7, b = t & 127;                  // t = l*128 + b
    int d = lane * 8;
    int idx = b * NL + l;
    int e = element[idx];
    int a = aroma[idx];
    int c = charge[idx] + 6;
    int s = segment[idx];
    float acc[8] = {0, 0, 0, 0, 0, 0, 0, 0};
    add8f(acc, E_elem  + (size_t)e * DIM + d);
    add8f(acc, pe      + (size_t)l * DIM + d);
    add8f(acc, E_aroma + (size_t)a * DIM + d);
    add8f(acc, E_charge+ (size_t)c * DIM + d);
    add8f(acc, E_seg   + (size_t)s * DIM + d);
    f32x8 o32; u16x8 o16;
#pragma unroll
    for (int i = 0; i < 8; i++) { o32[i] = acc[i]; o16[i] = f2bf(acc[i]); }
    *(f32x8*)(emb32 + (size_t)t * DIM + d) = o32;
    *(u16x8*)(emb16 + (size_t)t * DIM + d) = o16;
}

// -------- GEMM: C[M,N] = A[M,K] @ BT[N,K]^T (+f32 bias, relu, bf16/f32 resid) --
// Round-3 structure: 256x256 tile, BK=64, double-buffered LDS (128 KB),
// 512 threads = 8 waves (2M x 4N), per-wave 128x64 = acc[8][4].
// ONE barrier per 64-K tile: {vmcnt(0); s_barrier; issue all 8 GLL for t+1;
// 24 ds_read_b128 + 64 MFMA as a single compiler-scheduled region}.
//   - drain-to-0 is safe here: tile t+1's loads are issued a FULL tile
//     (~2400 cy) before their wait -- far beyond the ~900 cy HBM latency, so
//     nothing is hot-waited; the "keep loads in flight across the stall"
//     mechanism of counted vmcnt is preserved with 2 buffers.
//   - removing the per-phase barriers lets waves drift and the compiler's
//     fine lgkmcnt scheduling overlap LDS reads with MFMA across waves
//     (round-2's 4 lockstep barriers/64K serialized the two pipes: 3525
//     cy/tile measured vs ~2400 balanced).
// Race-freedom: GLL(t+1) -> buf (t+1)&1 = buf (t-1)&1; every wave's tile t-1
//   ds_reads are register-consumed (compiler lgkmcnt before its t-1 MFMAs)
//   before it reaches the boundary-t barrier, and GLL(t+1) is issued after
//   that barrier => no overwrite-while-read. Boundary vmcnt(0)+barrier =>
//   all waves' tile-t stages landed before anyone reads tile t.
// Swizzle: 8 chunks of 16B per row; LDS[R][c] holds global chunk c^(R&7)
//   (pre-swizzled source, linear GLL dest -- m104); fragment reads use
//   chunk (s*4+fq)^(fr&7): 2 lanes/chunk-column => 2-way = free.
// Requires M%256==0, N%256==0, K%64==0 (all our shapes: K=512/2048).
__global__ __launch_bounds__(512, 2) void gemm_bt(
    const u16* __restrict__ A, const u16* __restrict__ BT,
    const float* __restrict__ bias, const u16* __restrict__ resid16,
    const float* __restrict__ resid32,
    u16* __restrict__ C, int M, int N, int K, int do_relu) {
    // staging: A[2][256*64] @ 0 (64 KB), B[2][256*64] @ 32768 u16 (64 KB).
    // epilogue reuses smem as [256][264] u16 = 132 KB.
    __shared__ __align__(16) u16 smem[256 * 264];

    const int tid  = threadIdx.x;
    const int wave = tid >> 6;
    const int lane = tid & 63;

    // XCD-aware swizzle (bijective when nwg%8==0 -- all our grids), N-fastest.
    const int nwg = gridDim.x;
    const int bid = blockIdx.x;
    const int wg  = ((nwg & 7) == 0) ? ((bid & 7) * (nwg >> 3) + (bid >> 3)) : bid;
    const int nt  = N >> 8;                 // N-tiles of 256
    const int m0  = (wg / nt) * 256;
    const int n0  = (wg % nt) * 256;

    const int wmh = wave >> 2;          // 0..1 : wave's A row-half (128 rows)
    const int wnq = wave & 3;           // 0..3 : wave's B row-quarter (64 rows)
    const int fr  = lane & 15;          // fragment row/col
    const int fq  = lane >> 4;          // fragment k-quad
    // swizzled read chunks (u16 offsets) for k-slot 0 / 1
    const int ck0 = ((fq ^ (fr & 7)) * 8);
    const int ck1 = (((4 | fq) ^ (fr & 7)) * 8);   // 4+fq == 4|fq for fq<4

    // staging: 8 threads per row (8 chunks of 8 u16), 64 rows per GLL round.
    const int sRow = tid >> 3;                       // 0..63
    const int sChk = ((tid & 7) ^ (sRow & 7)) * 8;   // pre-swizzled SOURCE chunk
    const int ldst = sRow * 64 + (tid & 7) * 8;      // LINEAR lds dest (u16)

    const u16* Asrc = A  + (size_t)(m0 + sRow) * K + sChk;
    const u16* Bsrc = BT + (size_t)(n0 + sRow) * K + sChk;

    f32x4 acc[8][4] = {};

#define GLL(gp, lp) __builtin_amdgcn_global_load_lds(                            \
        (const __attribute__((address_space(1))) void*)(gp),                     \
        (__attribute__((address_space(3))) void*)(lp), 16, 0, 0)
#define STAGE(buf, kt) do {                                                      \
    GLL(Asrc + (size_t)(kt) * 64,                 &smem[(buf)*16384 +        ldst]); \
    GLL(Bsrc + (size_t)(kt) * 64,                 &smem[32768 + (buf)*16384 +        ldst]); \
    GLL(Asrc + (size_t)(kt) * 64 + (size_t) 64*K, &smem[(buf)*16384 +  4096 + ldst]); \
    GLL(Bsrc + (size_t)(kt) * 64 + (size_t) 64*K, &smem[32768 + (buf)*16384 +  4096 + ldst]); \
    GLL(Asrc + (size_t)(kt) * 64 + (size_t)128*K, &smem[(buf)*16384 +  8192 + ldst]); \
    GLL(Bsrc + (size_t)(kt) * 64 + (size_t)128*K, &smem[32768 + (buf)*16384 +  8192 + ldst]); \
    GLL(Asrc + (size_t)(kt) * 64 + (size_t)192*K, &smem[(buf)*16384 + 12288 + ldst]); \
    GLL(Bsrc + (size_t)(kt) * 64 + (size_t)192*K, &smem[32768 + (buf)*16384 + 12288 + ldst]); \
} while (0)

    const int nk = K >> 6;   // 8 or 32 here
    STAGE(0, 0);             // tile 0 in flight (8 GLL)

    for (int t = 0; t < nk; ++t) {
        // boundary: tile t's 8 loads are the only outstanding vmem; the wait
        // is a full tile after their issue, so it is (nearly) free.
        asm volatile("s_waitcnt vmcnt(0)\n\ts_barrier" ::: "memory");
        if (t + 1 < nk) STAGE((t + 1) & 1, t + 1);   // in flight across tile t

        const u16* Ab = &smem[(t & 1) * 16384];
        const u16* Bb = &smem[32768 + (t & 1) * 16384];
#pragma unroll
        for (int s = 0; s < 2; ++s) {
            const int ck = s ? ck1 : ck0;
            bf16x8 af[8], bg[4];
#pragma unroll
            for (int i = 0; i < 8; ++i)
                af[i] = *(const bf16x8*)(&Ab[(wmh * 128 + i * 16 + fr) * 64 + ck]);
#pragma unroll
            for (int j = 0; j < 4; ++j)
                bg[j] = *(const bf16x8*)(&Bb[(wnq * 64 + j * 16 + fr) * 64 + ck]);

            __builtin_amdgcn_s_setprio(1);
#pragma unroll
            for (int i = 0; i < 8; ++i)
#pragma unroll
                for (int j = 0; j < 4; ++j)
                    acc[i][j] = __builtin_amdgcn_mfma_f32_16x16x32_bf16(
                        af[i], bg[j], acc[i][j], 0, 0, 0);
            __builtin_amdgcn_s_setprio(0);
        }
    }
#undef STAGE
#undef GLL

    // ---- epilogue: bias/relu/resid in-register, stage bf16 tile to LDS, ----
    // ---- then fully-coalesced dwordx4 stores. ------------------------------
    // C/D layout: col = lane&15 (n), row = (lane>>4)*4 + reg (m)
    __syncthreads();   // all waves past final LDS reads; all vmem drained
#define CSTR 264       // 256 + 8 u16 pad
#pragma unroll
    for (int j = 0; j < 4; j++) {
        int n = n0 + wnq * 64 + j * 16 + fr;
        float bv = bias[n];
#pragma unroll
        for (int i = 0; i < 8; i++) {
#pragma unroll
            for (int r = 0; r < 4; r++) {
                int m = m0 + wmh * 128 + i * 16 + fq * 4 + r;
                float v = acc[i][j][r] + bv;
                if (do_relu) v = fmaxf(v, 0.0f);
                if (resid16) v += bf2f(resid16[(size_t)m * N + n]);
                if (resid32) v += resid32[(size_t)m * N + n];
                smem[(wmh * 128 + i * 16 + fq * 4 + r) * CSTR + wnq * 64 + j * 16 + fr] = f2bf(v);
            }
        }
    }
    __syncthreads();
    {
        const int erow = tid >> 5;         // 0..15
        const int ecol = (tid & 31) * 8;   // 32 lanes x 8 u16 = 256 cols
#pragma unroll
        for (int rr = 0; rr < 16; ++rr) {
            int row = rr * 16 + erow;
            *(u16x8*)(C + (size_t)(m0 + row) * N + n0 + ecol) =
                *(const u16x8*)(&smem[row * CSTR + ecol]);
        }
    }
#undef CSTR
}

// -------- aggregation + final residual (in-place on d_out, f32) --------
// out[t=l*B+b][d] = emb32[t][d] + sum_m (bond[b,l,m]!=l) * msg[bond*B+b][d]
__global__ void agg_kernel(const float* __restrict__ emb32, const u16* __restrict__ msg,
                           const int* __restrict__ bond, float* __restrict__ out) {
    int t = blockIdx.x * 4 + (threadIdx.x >> 6);  // one wave per token
    int lane = threadIdx.x & 63;
    int l = t >> 7, b = t & 127;
    int d = lane * 8;
    float acc[8];
    {
        f32x8 v = *(const f32x8*)(emb32 + (size_t)t * DIM + d);
#pragma unroll
        for (int i = 0; i < 8; i++) acc[i] = v[i];
    }
    const int* bp = bond + ((size_t)b * NL + l) * 6;
#pragma unroll
    for (int m = 0; m < 6; m++) {
        int j = bp[m];
        if (j != l) {  // wave-uniform branch
            u16x8 g = *(const u16x8*)(msg + ((size_t)j * NB + b) * DIM + d);
#pragma unroll
            for (int i = 0; i < 8; i++) acc[i] += bf2f(g[i]);
        }
    }
    f32x8 o;
#pragma unroll
    for (int i = 0; i < 8; i++) o[i] = acc[i];
    *(f32x8*)(out + (size_t)t * DIM + d) = o;
}

extern "C" void kernel_launch(void* const* d_in, const int* in_sizes, int n_in,
                              void* d_out, int out_size, void* d_ws, size_t ws_size,
                              hipStream_t stream) {
    const int* element = (const int*)d_in[0];
    const int* bond    = (const int*)d_in[1];
    const int* aroma   = (const int*)d_in[2];
    const int* charge  = (const int*)d_in[3];
    const int* segment = (const int*)d_in[4];
    const float* pe      = (const float*)d_in[5];
    const float* E_elem  = (const float*)d_in[6];
    const float* E_charge= (const float*)d_in[7];
    const float* E_aroma = (const float*)d_in[8];
    const float* E_seg   = (const float*)d_in[9];
    const float* W1 = (const float*)d_in[10];
    const float* b1 = (const float*)d_in[11];
    const float* W2 = (const float*)d_in[12];
    const float* b2 = (const float*)d_in[13];
    const float* W3 = (const float*)d_in[14];
    const float* b3 = (const float*)d_in[15];
    const float* W4 = (const float*)d_in[16];
    const float* b4 = (const float*)d_in[17];
    const float* W5 = (const float*)d_in[18];
    const float* b5 = (const float*)d_in[19];

    // f32 emb lives in d_out (50 MiB); agg rewrites d_out in place at the end.
    float* emb32 = (float*)d_out;

    // dynamic ws layout — never exceed ws_size
    char* ws = (char*)d_ws;
    size_t woff = 0;
    auto take = [&](size_t bytes) -> u16* {
        u16* p = (u16*)(ws + woff);
        woff += (bytes + 255) & ~(size_t)255;
        return p;
    };
    u16* W1T = take((size_t)HID * DIM * 2);   // 2048x512 bf16
    u16* W2T = take((size_t)DIM * HID * 2);   // 512x2048
    u16* W3T = take((size_t)HID * DIM * 2);
    u16* W4T = take((size_t)DIM * HID * 2);
    u16* W5T = take((size_t)DIM * DIM * 2);
    u16* emb16 = take((size_t)NTOK * DIM * 2);  // 24 MiB
    u16* msg   = take((size_t)NTOK * DIM * 2);  // 24 MiB

    // pick largest M-chunk that fits: h(CM x HID) + xa,xb(CM x DIM), bf16.
    // CM must be a multiple of 256 (gemm tile height).
    static const int ncs[] = {1, 2, 3, 4, 6, 8, 12, 16, 24, 32, 48, 96};
    int CM = 256;
    for (int nc : ncs) {
        int cm = NTOK / nc;
        if (cm % 256 != 0) continue;
        size_t need = woff + ((size_t)cm * HID * 2 + 256)
                           + ((size_t)cm * DIM * 2 + 256) * 2;
        if (need <= ws_size) { CM = cm; break; }
    }
    u16* hC  = take((size_t)CM * HID * 2);
    u16* xaC = take((size_t)CM * DIM * 2);
    u16* xbC = take((size_t)CM * DIM * 2);

    // weight transposes + cast: f32 (K,N) -> bf16 (N,K)
    transpose_f2b<<<dim3(HID / 32, DIM / 32), 256, 0, stream>>>(W1, W1T, DIM, HID);
    transpose_f2b<<<dim3(DIM / 32, HID / 32), 256, 0, stream>>>(W2, W2T, HID, DIM);
    transpose_f2b<<<dim3(HID / 32, DIM / 32), 256, 0, stream>>>(W3, W3T, DIM, HID);
    transpose_f2b<<<dim3(DIM / 32, HID / 32), 256, 0, stream>>>(W4, W4T, HID, DIM);
    transpose_f2b<<<dim3(DIM / 32, DIM / 32), 256, 0, stream>>>(W5, W5T, DIM, DIM);

    embed_kernel<<<NTOK / 4, 256, 0, stream>>>(element, aroma, charge, segment, pe,
                                               E_elem, E_charge, E_aroma, E_seg,
                                               emb32, emb16);

    // MLP per M-chunk: x += relu(x@W1+b1)@W2+b2 ; x += relu(x@W3+b3)@W4+b4 ; msg = x@W5+b5
    for (int c0 = 0; c0 < NTOK; c0 += CM) {
        const u16* x16 = emb16 + (size_t)c0 * DIM;
        const float* x32 = emb32 + (size_t)c0 * DIM;
        u16* msgC = msg + (size_t)c0 * DIM;
        int mt = CM / 256;
        gemm_bt<<<dim3(mt * (HID / 256)), 512, 0, stream>>>(x16, W1T, b1, nullptr, nullptr, hC,  CM, HID, DIM, 1);
        gemm_bt<<<dim3(mt * (DIM / 256)), 512, 0, stream>>>(hC,  W2T, b2, nullptr, x32,     xaC, CM, DIM, HID, 0);
        gemm_bt<<<dim3(mt * (HID / 256)), 512, 0, stream>>>(xaC, W3T, b3, nullptr, nullptr, hC,  CM, HID, DIM, 1);
        gemm_bt<<<dim3(mt * (DIM / 256)), 512, 0, stream>>>(hC,  W4T, b4, xaC,    nullptr,  xbC, CM, DIM, HID, 0);
        gemm_bt<<<dim3(mt * (DIM / 256)), 512, 0, stream>>>(xbC, W5T, b5, nullptr, nullptr, msgC, CM, DIM, DIM, 0);
    }

    agg_kernel<<<NTOK / 4, 256, 0, stream>>>(emb32, msg, bond, (float*)d_out);
}